// Round 6
// baseline (234.913 us; speedup 1.0000x reference)
//
#include <hip/hip_runtime.h>
#include <hip/hip_bf16.h>
#include <hip/hip_fp16.h>

// GCN 3-layer: out = A_hat @ (A_hat @ relu(A_hat @ relu(X W1)+b1 ... ) )
// R2: agg vectorized + unrolled. R3: GEMM W-only-LDS, 8x8 reg tile.
// R4: fp16 gather table + packed 8B edge records.
// R5: 3-stage device-wide scan; dinv fused into write_offsets.
// R6: hipMemsetAsync(counts) was captured as a pathological 42us fill kernel
//     (200KB @ 5GB/s) inside the timed graph -> replaced with our own
//     grid-stride zero kernel (~2us).

__device__ inline float4 h4_to_f4(float2 raw) {
    __half2 lo = *reinterpret_cast<__half2*>(&raw.x);
    __half2 hi = *reinterpret_cast<__half2*>(&raw.y);
    float2 a = __half22float2(lo);
    float2 b = __half22float2(hi);
    return make_float4(a.x, a.y, b.x, b.y);
}

__device__ inline float2 f4_to_h4(float4 v) {
    __half2 lo = __floats2half2_rn(v.x, v.y);
    __half2 hi = __floats2half2_rn(v.z, v.w);
    float2 r;
    r.x = *reinterpret_cast<float*>(&lo);
    r.y = *reinterpret_cast<float*>(&hi);
    return r;
}

// Zero counts[n] (int), vectorized int4. Replaces runtime fillBuffer (42us -> ~2us).
__global__ __launch_bounds__(256) void zero_counts_kernel(int4* __restrict__ p, int n4) {
    int i = blockIdx.x * 256 + threadIdx.x;
    if (i < n4) p[i] = make_int4(0, 0, 0, 0);
}

__global__ void count_edges_kernel(const int* __restrict__ col, int* __restrict__ counts, int E) {
    int e = blockIdx.x * blockDim.x + threadIdx.x;
    if (e < E) atomicAdd(&counts[col[e]], 1);
}

// Stage 1: per-block (256 elements) sum of counts.
__global__ __launch_bounds__(256) void block_sum_kernel(const int* __restrict__ counts,
                                                        int* __restrict__ blocksum, int n) {
    int i = blockIdx.x * 256 + threadIdx.x;
    int v = (i < n) ? counts[i] : 0;
    #pragma unroll
    for (int d = 1; d < 64; d <<= 1) v += __shfl_xor(v, d);
    __shared__ int ws[4];
    if ((threadIdx.x & 63) == 0) ws[threadIdx.x >> 6] = v;
    __syncthreads();
    if (threadIdx.x == 0) blocksum[blockIdx.x] = ws[0] + ws[1] + ws[2] + ws[3];
}

// Stage 2: one block scans nb (<=256) block sums -> exclusive blockoff; offsets[n]=total.
__global__ __launch_bounds__(256) void scan_sums_kernel(const int* __restrict__ blocksum,
                                                        int* __restrict__ blockoff,
                                                        int* __restrict__ offsets, int nb, int n) {
    int tid = threadIdx.x;
    int lane = tid & 63, wid = tid >> 6;
    int orig = (tid < nb) ? blocksum[tid] : 0;
    int v = orig;
    #pragma unroll
    for (int d = 1; d < 64; d <<= 1) {
        int u = __shfl_up(v, d);
        if (lane >= d) v += u;
    }
    __shared__ int ws[4];
    if (lane == 63) ws[wid] = v;
    __syncthreads();
    int add = 0;
    for (int w = 0; w < wid; ++w) add += ws[w];
    v += add;                                  // inclusive
    if (tid < nb) blockoff[tid] = v - orig;    // exclusive
    if (tid == 255) offsets[n] = v;            // tail zeros -> total
}

// Stage 3: intra-chunk exclusive scan + blockoff -> offsets; zero cursor; fused dinv.
__global__ __launch_bounds__(256) void write_offsets_kernel(const int* __restrict__ counts,
                                                            const int* __restrict__ blockoff,
                                                            int* __restrict__ offsets,
                                                            int* __restrict__ cursor,
                                                            float* __restrict__ dinv, int n) {
    int tid = threadIdx.x;
    int i = blockIdx.x * 256 + tid;
    int lane = tid & 63, wid = tid >> 6;
    int c = (i < n) ? counts[i] : 0;
    int v = c;
    #pragma unroll
    for (int d = 1; d < 64; d <<= 1) {
        int u = __shfl_up(v, d);
        if (lane >= d) v += u;
    }
    __shared__ int ws[4];
    if (lane == 63) ws[wid] = v;
    __syncthreads();
    int add = 0;
    for (int w = 0; w < wid; ++w) add += ws[w];
    int incl = v + add;
    if (i < n) {
        offsets[i] = blockoff[blockIdx.x] + incl - c;
        cursor[i] = 0;
        dinv[i] = rsqrtf((float)(c + 1));      // +1 self loop
    }
}

// One 8B scattered store per edge: (src, bitcast(wnorm)).
__global__ void fill_csr_kernel(const int* __restrict__ row, const int* __restrict__ col,
                                const int* __restrict__ offsets, int* __restrict__ cursor,
                                const float* __restrict__ dinv,
                                int2* __restrict__ edges, int E) {
    int e = blockIdx.x * blockDim.x + threadIdx.x;
    if (e < E) {
        int c = col[e];
        int r = row[e];
        int pos = offsets[c] + atomicAdd(&cursor[c], 1);
        edges[pos] = make_int2(r, __float_as_int(dinv[r] * dinv[c]));
    }
}

// out16[n, DO] (fp16) = A[n,128] @ W[128, DO]; f32 accumulation, f16 store.
// Thread (rt, ct): 8 contiguous rows x 8 cols (two 4-col chunks DO/2 apart).
// W in LDS (16B lane stride -> conflict-free); A wave-broadcast from global.
template <int DO>
__global__ __launch_bounds__(256, 2) void gemm_kernel(const float* __restrict__ A,
                                                      const float* __restrict__ W,
                                                      __half* __restrict__ out, int n) {
    constexpr int K = 128;
    constexpr int COLTH = DO / 8;          // 16 (DO=128) or 8 (DO=64)
    constexpr int ROWTH = 256 / COLTH;     // 16 or 32
    constexpr int R = 8;                   // rows per thread
    constexpr int BR = ROWTH * R;          // 128 or 256 rows per block
    constexpr int HALF = DO / 2;

    __shared__ float Wl[K * DO];           // 64 KB (DO=128) / 32 KB (DO=64)

    int tid = threadIdx.x;
    #pragma unroll
    for (int q = tid; q < K * DO / 4; q += 256) {
        ((float4*)Wl)[q] = ((const float4*)W)[q];
    }
    __syncthreads();

    int ct = tid % COLTH;
    int rt = tid / COLTH;
    int rb = blockIdx.x * BR + rt * R;

    const float4* A4 = (const float4*)A;

    int rowc[R];
    #pragma unroll
    for (int i = 0; i < R; ++i) {
        int row = rb + i;
        rowc[i] = (row < n) ? row : (n - 1);
    }

    float4 acc[R][2];
    #pragma unroll
    for (int i = 0; i < R; ++i) {
        acc[i][0].x = acc[i][0].y = acc[i][0].z = acc[i][0].w = 0.f;
        acc[i][1].x = acc[i][1].y = acc[i][1].z = acc[i][1].w = 0.f;
    }

    #pragma unroll 2
    for (int k4 = 0; k4 < K / 4; ++k4) {
        float4 areg[R];
        #pragma unroll
        for (int i = 0; i < R; ++i) {
            areg[i] = A4[(size_t)rowc[i] * (K / 4) + k4];
        }
        #pragma unroll
        for (int q = 0; q < 4; ++q) {
            int k = k4 * 4 + q;
            float4 w0 = *(const float4*)(Wl + k * DO + ct * 4);
            float4 w1 = *(const float4*)(Wl + k * DO + HALF + ct * 4);
            #pragma unroll
            for (int i = 0; i < R; ++i) {
                float a = (q == 0) ? areg[i].x : (q == 1) ? areg[i].y
                        : (q == 2) ? areg[i].z : areg[i].w;
                acc[i][0].x += a * w0.x; acc[i][0].y += a * w0.y;
                acc[i][0].z += a * w0.z; acc[i][0].w += a * w0.w;
                acc[i][1].x += a * w1.x; acc[i][1].y += a * w1.y;
                acc[i][1].z += a * w1.z; acc[i][1].w += a * w1.w;
            }
        }
    }

    #pragma unroll
    for (int i = 0; i < R; ++i) {
        int row = rb + i;
        if (row < n) {
            *(float2*)(out + (size_t)row * DO + ct * 4) = f4_to_h4(acc[i][0]);
            *(float2*)(out + (size_t)row * DO + HALF + ct * 4) = f4_to_h4(acc[i][1]);
        }
    }
}

// out[d] = bias + hw[d]*dinv[d]^2 + sum_e hw16[src(e)] * wnorm(e)   (f32 acc)
// TPD = DO/4 lanes/dest, each lane covers 4 cols (8B f16 gather). Unroll x8.
template <int DO, bool RELU>
__global__ __launch_bounds__(256) void agg_kernel(const __half* __restrict__ hw,
                                                  const int* __restrict__ offsets,
                                                  const int2* __restrict__ edges,
                                                  const float* __restrict__ dinv,
                                                  const float* __restrict__ bias,
                                                  float* __restrict__ out, int n) {
    constexpr int TPD = DO / 4;            // lanes per dest
    constexpr int DPB = 256 / TPD;         // dests per block
    int d = blockIdx.x * DPB + threadIdx.x / TPD;
    int j = threadIdx.x % TPD;             // 4-col chunk index
    if (d >= n) return;

    const float2* hw2 = (const float2*)hw; // 4 halves per unit
    int beg = offsets[d];
    int end = offsets[d + 1];
    float di = dinv[d];
    float sw = di * di;

    float4 b4 = ((const float4*)bias)[j];
    float4 self = h4_to_f4(hw2[(size_t)d * TPD + j]);
    float4 acc;
    acc.x = b4.x + self.x * sw;
    acc.y = b4.y + self.y * sw;
    acc.z = b4.z + self.z * sw;
    acc.w = b4.w + self.w * sw;

    int e = beg;
    #define EDGE_FMA(EE) do {                                            \
        int2 er = edges[EE];                                             \
        float w = __int_as_float(er.y);                                  \
        float4 v = h4_to_f4(hw2[(size_t)er.x * TPD + j]);                \
        acc.x += v.x * w; acc.y += v.y * w;                              \
        acc.z += v.z * w; acc.w += v.w * w;                              \
    } while (0)

    for (; e + 8 <= end; e += 8) {
        int2 r0 = edges[e + 0], r1 = edges[e + 1], r2 = edges[e + 2], r3 = edges[e + 3];
        int2 r4 = edges[e + 4], r5 = edges[e + 5], r6 = edges[e + 6], r7 = edges[e + 7];
        float4 v0 = h4_to_f4(hw2[(size_t)r0.x * TPD + j]);
        float4 v1 = h4_to_f4(hw2[(size_t)r1.x * TPD + j]);
        float4 v2 = h4_to_f4(hw2[(size_t)r2.x * TPD + j]);
        float4 v3 = h4_to_f4(hw2[(size_t)r3.x * TPD + j]);
        float4 v4 = h4_to_f4(hw2[(size_t)r4.x * TPD + j]);
        float4 v5 = h4_to_f4(hw2[(size_t)r5.x * TPD + j]);
        float4 v6 = h4_to_f4(hw2[(size_t)r6.x * TPD + j]);
        float4 v7 = h4_to_f4(hw2[(size_t)r7.x * TPD + j]);
        float w0 = __int_as_float(r0.y), w1 = __int_as_float(r1.y);
        float w2 = __int_as_float(r2.y), w3 = __int_as_float(r3.y);
        float w4 = __int_as_float(r4.y), w5 = __int_as_float(r5.y);
        float w6 = __int_as_float(r6.y), w7 = __int_as_float(r7.y);
        acc.x += v0.x * w0; acc.y += v0.y * w0; acc.z += v0.z * w0; acc.w += v0.w * w0;
        acc.x += v1.x * w1; acc.y += v1.y * w1; acc.z += v1.z * w1; acc.w += v1.w * w1;
        acc.x += v2.x * w2; acc.y += v2.y * w2; acc.z += v2.z * w2; acc.w += v2.w * w2;
        acc.x += v3.x * w3; acc.y += v3.y * w3; acc.z += v3.z * w3; acc.w += v3.w * w3;
        acc.x += v4.x * w4; acc.y += v4.y * w4; acc.z += v4.z * w4; acc.w += v4.w * w4;
        acc.x += v5.x * w5; acc.y += v5.y * w5; acc.z += v5.z * w5; acc.w += v5.w * w5;
        acc.x += v6.x * w6; acc.y += v6.y * w6; acc.z += v6.z * w6; acc.w += v6.w * w6;
        acc.x += v7.x * w7; acc.y += v7.y * w7; acc.z += v7.z * w7; acc.w += v7.w * w7;
    }
    for (; e + 4 <= end; e += 4) {
        int2 r0 = edges[e + 0], r1 = edges[e + 1], r2 = edges[e + 2], r3 = edges[e + 3];
        float4 v0 = h4_to_f4(hw2[(size_t)r0.x * TPD + j]);
        float4 v1 = h4_to_f4(hw2[(size_t)r1.x * TPD + j]);
        float4 v2 = h4_to_f4(hw2[(size_t)r2.x * TPD + j]);
        float4 v3 = h4_to_f4(hw2[(size_t)r3.x * TPD + j]);
        float w0 = __int_as_float(r0.y), w1 = __int_as_float(r1.y);
        float w2 = __int_as_float(r2.y), w3 = __int_as_float(r3.y);
        acc.x += v0.x * w0; acc.y += v0.y * w0; acc.z += v0.z * w0; acc.w += v0.w * w0;
        acc.x += v1.x * w1; acc.y += v1.y * w1; acc.z += v1.z * w1; acc.w += v1.w * w1;
        acc.x += v2.x * w2; acc.y += v2.y * w2; acc.z += v2.z * w2; acc.w += v2.w * w2;
        acc.x += v3.x * w3; acc.y += v3.y * w3; acc.z += v3.z * w3; acc.w += v3.w * w3;
    }
    for (; e < end; ++e) EDGE_FMA(e);
    #undef EDGE_FMA

    if (RELU) {
        acc.x = fmaxf(acc.x, 0.f); acc.y = fmaxf(acc.y, 0.f);
        acc.z = fmaxf(acc.z, 0.f); acc.w = fmaxf(acc.w, 0.f);
    }
    ((float4*)out)[(size_t)d * TPD + j] = acc;
}

extern "C" void kernel_launch(void* const* d_in, const int* in_sizes, int n_in,
                              void* d_out, int out_size, void* d_ws, size_t ws_size,
                              hipStream_t stream) {
    const float* x  = (const float*)d_in[0];
    const float* W1 = (const float*)d_in[1];
    const float* b1 = (const float*)d_in[2];
    const float* W2 = (const float*)d_in[3];
    const float* b2 = (const float*)d_in[4];
    const float* W3 = (const float*)d_in[5];
    const float* b3 = (const float*)d_in[6];
    const int*   ei = (const int*)d_in[7];

    const int N = in_sizes[0] / 128;
    const int E = in_sizes[7] / 2;
    const int* rowi = ei;       // edge_index[0] = sources
    const int* coli = ei + E;   // edge_index[1] = targets

    float* out = (float*)d_out;

    // workspace carve-up (256B aligned)
    char* ws = (char*)d_ws;
    size_t off = 0;
    auto alloc = [&](size_t bytes) -> void* {
        void* p = ws + off;
        off = (off + bytes + 255) & ~(size_t)255;
        return p;
    };
    const int NB = (N + 255) / 256;        // scan blocks (196 for N=50000)
    float* dinv     = (float*)alloc((size_t)N * 4);
    int*   counts   = (int*)  alloc(((size_t)N + 4) * 4);  // int4-padded
    int*   offsets  = (int*)  alloc((size_t)(N + 1) * 4);
    int*   cursor   = (int*)  alloc((size_t)N * 4);
    int*   blocksum = (int*)  alloc((size_t)NB * 4);
    int*   blockoff = (int*)  alloc((size_t)NB * 4);
    int2*  edges    = (int2*) alloc((size_t)E * 8);
    __half* hw16    = (__half*)alloc((size_t)N * 128 * 2);
    float* hbuf     = (float*)alloc((size_t)N * 128 * 4);

    // ---- degree / norm / CSR ----
    const int n4 = (N + 3) / 4;
    zero_counts_kernel<<<(n4 + 255) / 256, 256, 0, stream>>>((int4*)counts, n4);
    count_edges_kernel<<<(E + 255) / 256, 256, 0, stream>>>(coli, counts, E);
    block_sum_kernel<<<NB, 256, 0, stream>>>(counts, blocksum, N);
    scan_sums_kernel<<<1, 256, 0, stream>>>(blocksum, blockoff, offsets, NB, N);
    write_offsets_kernel<<<NB, 256, 0, stream>>>(counts, blockoff, offsets, cursor, dinv, N);
    fill_csr_kernel<<<(E + 255) / 256, 256, 0, stream>>>(rowi, coli, offsets, cursor, dinv, edges, E);

    // ---- layer 1: hw16 = f16(x @ W1); h = relu(agg(hw16) + b1) ----
    gemm_kernel<128><<<(N + 127) / 128, 256, 0, stream>>>(x, W1, hw16, N);
    agg_kernel<128, true><<<(N + 7) / 8, 256, 0, stream>>>(hw16, offsets, edges, dinv, b1, hbuf, N);

    // ---- layer 2 ----
    gemm_kernel<128><<<(N + 127) / 128, 256, 0, stream>>>(hbuf, W2, hw16, N);
    agg_kernel<128, true><<<(N + 7) / 8, 256, 0, stream>>>(hw16, offsets, edges, dinv, b2, hbuf, N);

    // ---- layer 3 (no relu), width 64, write d_out ----
    gemm_kernel<64><<<(N + 255) / 256, 256, 0, stream>>>(hbuf, W3, hw16, N);
    agg_kernel<64, false><<<(N + 15) / 16, 256, 0, stream>>>(hw16, offsets, edges, dinv, b3, out, N);
}

// Round 7
// 221.016 us; speedup vs baseline: 1.0629x; 1.0629x over previous
//
#include <hip/hip_runtime.h>
#include <hip/hip_bf16.h>
#include <hip/hip_fp16.h>

// GCN 3-layer: out = A_hat @ (A_hat @ relu(A_hat @ relu(X W1)+b1 ... ) )
// R2: agg vectorized + unrolled. R3: GEMM W-only-LDS, 8x8 reg tile.
// R4: fp16 gather table + packed 8B edge records.
// R5: 3-stage device-wide scan. R6: own zero kernel (memset was harness-side
//     poison, not ours -> neutral; lesson logged).
// R7: fdot2 (v_dot2_f32_f16) GEMM — f16 A (x converted once; agg writes f16),
//     f16 W packed as k-pairs in LDS (32/16KB). Halves GEMM VALU issue count.
//     All accumulation stays f32.

typedef _Float16 h2 __attribute__((ext_vector_type(2)));
typedef _Float16 h8 __attribute__((ext_vector_type(8)));

__device__ inline float4 h4_to_f4(float2 raw) {
    __half2 lo = *reinterpret_cast<__half2*>(&raw.x);
    __half2 hi = *reinterpret_cast<__half2*>(&raw.y);
    float2 a = __half22float2(lo);
    float2 b = __half22float2(hi);
    return make_float4(a.x, a.y, b.x, b.y);
}

__device__ inline uint pack_h2(float a, float b) {
    __half2 h = __floats2half2_rn(a, b);
    return *reinterpret_cast<uint*>(&h);
}

// Zero counts[n] (int), vectorized int4.
__global__ __launch_bounds__(256) void zero_counts_kernel(int4* __restrict__ p, int n4) {
    int i = blockIdx.x * 256 + threadIdx.x;
    if (i < n4) p[i] = make_int4(0, 0, 0, 0);
}

// f32 -> f16, 4 elems/thread.
__global__ __launch_bounds__(256) void f32_to_f16_kernel(const float4* __restrict__ in,
                                                         uint2* __restrict__ out, int n4) {
    int i = blockIdx.x * 256 + threadIdx.x;
    if (i < n4) {
        float4 v = in[i];
        out[i] = make_uint2(pack_h2(v.x, v.y), pack_h2(v.z, v.w));
    }
}

__global__ void count_edges_kernel(const int* __restrict__ col, int* __restrict__ counts, int E) {
    int e = blockIdx.x * blockDim.x + threadIdx.x;
    if (e < E) atomicAdd(&counts[col[e]], 1);
}

// Stage 1: per-block (256 elements) sum of counts.
__global__ __launch_bounds__(256) void block_sum_kernel(const int* __restrict__ counts,
                                                        int* __restrict__ blocksum, int n) {
    int i = blockIdx.x * 256 + threadIdx.x;
    int v = (i < n) ? counts[i] : 0;
    #pragma unroll
    for (int d = 1; d < 64; d <<= 1) v += __shfl_xor(v, d);
    __shared__ int ws[4];
    if ((threadIdx.x & 63) == 0) ws[threadIdx.x >> 6] = v;
    __syncthreads();
    if (threadIdx.x == 0) blocksum[blockIdx.x] = ws[0] + ws[1] + ws[2] + ws[3];
}

// Stage 2: one block scans nb (<=256) block sums -> exclusive blockoff; offsets[n]=total.
__global__ __launch_bounds__(256) void scan_sums_kernel(const int* __restrict__ blocksum,
                                                        int* __restrict__ blockoff,
                                                        int* __restrict__ offsets, int nb, int n) {
    int tid = threadIdx.x;
    int lane = tid & 63, wid = tid >> 6;
    int orig = (tid < nb) ? blocksum[tid] : 0;
    int v = orig;
    #pragma unroll
    for (int d = 1; d < 64; d <<= 1) {
        int u = __shfl_up(v, d);
        if (lane >= d) v += u;
    }
    __shared__ int ws[4];
    if (lane == 63) ws[wid] = v;
    __syncthreads();
    int add = 0;
    for (int w = 0; w < wid; ++w) add += ws[w];
    v += add;                                  // inclusive
    if (tid < nb) blockoff[tid] = v - orig;    // exclusive
    if (tid == 255) offsets[n] = v;            // tail zeros -> total
}

// Stage 3: intra-chunk exclusive scan + blockoff -> offsets; zero cursor; fused dinv.
__global__ __launch_bounds__(256) void write_offsets_kernel(const int* __restrict__ counts,
                                                            const int* __restrict__ blockoff,
                                                            int* __restrict__ offsets,
                                                            int* __restrict__ cursor,
                                                            float* __restrict__ dinv, int n) {
    int tid = threadIdx.x;
    int i = blockIdx.x * 256 + tid;
    int lane = tid & 63, wid = tid >> 6;
    int c = (i < n) ? counts[i] : 0;
    int v = c;
    #pragma unroll
    for (int d = 1; d < 64; d <<= 1) {
        int u = __shfl_up(v, d);
        if (lane >= d) v += u;
    }
    __shared__ int ws[4];
    if (lane == 63) ws[wid] = v;
    __syncthreads();
    int add = 0;
    for (int w = 0; w < wid; ++w) add += ws[w];
    int incl = v + add;
    if (i < n) {
        offsets[i] = blockoff[blockIdx.x] + incl - c;
        cursor[i] = 0;
        dinv[i] = rsqrtf((float)(c + 1));      // +1 self loop
    }
}

// One 8B scattered store per edge: (src, bitcast(wnorm)).
__global__ void fill_csr_kernel(const int* __restrict__ row, const int* __restrict__ col,
                                const int* __restrict__ offsets, int* __restrict__ cursor,
                                const float* __restrict__ dinv,
                                int2* __restrict__ edges, int E) {
    int e = blockIdx.x * blockDim.x + threadIdx.x;
    if (e < E) {
        int c = col[e];
        int r = row[e];
        int pos = offsets[c] + atomicAdd(&cursor[c], 1);
        edges[pos] = make_int2(r, __float_as_int(dinv[r] * dinv[c]));
    }
}

// out16[n, DO] (f16) = A16[n,128] @ W[128, DO]; v_dot2_f32_f16, f32 acc.
// W staged in LDS as k-pair-packed h2: Wl[k2*DO + c] = {W[2k2][c], W[2k2+1][c]}.
// Thread (rt, ct): R contiguous rows x 8 cols (two 4-col chunks DO/2 apart).
// Per k-pair: 2x ds_read_b128 (16B lane stride, conflict-free) + R*8 fdot2.
template <int DO>
__global__ __launch_bounds__(256, 2) void gemm16_kernel(const __half* __restrict__ A,
                                                        const float* __restrict__ W,
                                                        __half* __restrict__ out, int n) {
    constexpr int K = 128;
    constexpr int COLTH = DO / 8;          // 16 (DO=128) or 8 (DO=64)
    constexpr int ROWTH = 256 / COLTH;     // 16 or 32
    constexpr int R = (DO == 128) ? 8 : 4; // rows per thread
    constexpr int BR = ROWTH * R;          // 128 rows per block
    constexpr int HALF = DO / 2;

    __shared__ alignas(16) h2 Wl[(K / 2) * DO];  // 32 KB (DO=128) / 16 KB (DO=64)

    int tid = threadIdx.x;
    // stage W as packed k-pairs
    for (int idx = tid; idx < (K / 2) * (DO / 4); idx += 256) {
        int k2 = idx / (DO / 4);
        int c4 = idx % (DO / 4);
        float4 w0 = ((const float4*)(W + (size_t)(2 * k2) * DO))[c4];
        float4 w1 = ((const float4*)(W + (size_t)(2 * k2 + 1) * DO))[c4];
        h2* dst = &Wl[k2 * DO + c4 * 4];
        h2 d0; d0.x = (_Float16)w0.x; d0.y = (_Float16)w1.x; dst[0] = d0;
        h2 d1; d1.x = (_Float16)w0.y; d1.y = (_Float16)w1.y; dst[1] = d1;
        h2 d2; d2.x = (_Float16)w0.z; d2.y = (_Float16)w1.z; dst[2] = d2;
        h2 d3; d3.x = (_Float16)w0.w; d3.y = (_Float16)w1.w; dst[3] = d3;
    }
    __syncthreads();

    int ct = tid % COLTH;
    int rt = tid / COLTH;
    int rb = blockIdx.x * BR + rt * R;

    int rowc[R];
    #pragma unroll
    for (int i = 0; i < R; ++i) {
        int row = rb + i;
        rowc[i] = (row < n) ? row : (n - 1);
    }

    float acc[R][8];
    #pragma unroll
    for (int i = 0; i < R; ++i)
        #pragma unroll
        for (int c = 0; c < 8; ++c) acc[i][c] = 0.f;

    #pragma unroll 2
    for (int k8 = 0; k8 < K / 8; ++k8) {
        h8 av[R];
        #pragma unroll
        for (int i = 0; i < R; ++i) {
            av[i] = ((const h8*)(A + (size_t)rowc[i] * K))[k8];
        }
        #pragma unroll
        for (int kk = 0; kk < 4; ++kk) {
            int k2 = k8 * 4 + kk;
            h2 w0[4], w1[4];
            *(uint4*)w0 = *(const uint4*)(&Wl[k2 * DO + ct * 4]);
            *(uint4*)w1 = *(const uint4*)(&Wl[k2 * DO + HALF + ct * 4]);
            #pragma unroll
            for (int i = 0; i < R; ++i) {
                h2 a; a.x = av[i][2 * kk]; a.y = av[i][2 * kk + 1];
                #pragma unroll
                for (int c = 0; c < 4; ++c) {
                    acc[i][c]     = __builtin_amdgcn_fdot2(a, w0[c], acc[i][c], false);
                    acc[i][4 + c] = __builtin_amdgcn_fdot2(a, w1[c], acc[i][4 + c], false);
                }
            }
        }
    }

    #pragma unroll
    for (int i = 0; i < R; ++i) {
        int row = rb + i;
        if (row < n) {
            uint2 q0 = make_uint2(pack_h2(acc[i][0], acc[i][1]), pack_h2(acc[i][2], acc[i][3]));
            uint2 q1 = make_uint2(pack_h2(acc[i][4], acc[i][5]), pack_h2(acc[i][6], acc[i][7]));
            *(uint2*)(out + (size_t)row * DO + ct * 4) = q0;
            *(uint2*)(out + (size_t)row * DO + HALF + ct * 4) = q1;
        }
    }
}

// out[d] = bias + hw[d]*dinv[d]^2 + sum_e hw16[src(e)] * wnorm(e)   (f32 acc)
// TPD = DO/4 lanes/dest, 8B f16 gathers, unroll x8. F16OUT: write f16 (8B) else f32 (16B).
template <int DO, bool RELU, bool F16OUT>
__global__ __launch_bounds__(256) void agg_kernel(const __half* __restrict__ hw,
                                                  const int* __restrict__ offsets,
                                                  const int2* __restrict__ edges,
                                                  const float* __restrict__ dinv,
                                                  const float* __restrict__ bias,
                                                  void* __restrict__ outp, int n) {
    constexpr int TPD = DO / 4;            // lanes per dest
    constexpr int DPB = 256 / TPD;         // dests per block
    int d = blockIdx.x * DPB + threadIdx.x / TPD;
    int j = threadIdx.x % TPD;             // 4-col chunk index
    if (d >= n) return;

    const float2* hw2 = (const float2*)hw; // 4 halves per unit
    int beg = offsets[d];
    int end = offsets[d + 1];
    float di = dinv[d];
    float sw = di * di;

    float4 b4 = ((const float4*)bias)[j];
    float4 self = h4_to_f4(hw2[(size_t)d * TPD + j]);
    float4 acc;
    acc.x = b4.x + self.x * sw;
    acc.y = b4.y + self.y * sw;
    acc.z = b4.z + self.z * sw;
    acc.w = b4.w + self.w * sw;

    int e = beg;
    for (; e + 8 <= end; e += 8) {
        int2 r0 = edges[e + 0], r1 = edges[e + 1], r2 = edges[e + 2], r3 = edges[e + 3];
        int2 r4 = edges[e + 4], r5 = edges[e + 5], r6 = edges[e + 6], r7 = edges[e + 7];
        float4 v0 = h4_to_f4(hw2[(size_t)r0.x * TPD + j]);
        float4 v1 = h4_to_f4(hw2[(size_t)r1.x * TPD + j]);
        float4 v2 = h4_to_f4(hw2[(size_t)r2.x * TPD + j]);
        float4 v3 = h4_to_f4(hw2[(size_t)r3.x * TPD + j]);
        float4 v4 = h4_to_f4(hw2[(size_t)r4.x * TPD + j]);
        float4 v5 = h4_to_f4(hw2[(size_t)r5.x * TPD + j]);
        float4 v6 = h4_to_f4(hw2[(size_t)r6.x * TPD + j]);
        float4 v7 = h4_to_f4(hw2[(size_t)r7.x * TPD + j]);
        float w0 = __int_as_float(r0.y), w1 = __int_as_float(r1.y);
        float w2 = __int_as_float(r2.y), w3 = __int_as_float(r3.y);
        float w4 = __int_as_float(r4.y), w5 = __int_as_float(r5.y);
        float w6 = __int_as_float(r6.y), w7 = __int_as_float(r7.y);
        acc.x += v0.x * w0; acc.y += v0.y * w0; acc.z += v0.z * w0; acc.w += v0.w * w0;
        acc.x += v1.x * w1; acc.y += v1.y * w1; acc.z += v1.z * w1; acc.w += v1.w * w1;
        acc.x += v2.x * w2; acc.y += v2.y * w2; acc.z += v2.z * w2; acc.w += v2.w * w2;
        acc.x += v3.x * w3; acc.y += v3.y * w3; acc.z += v3.z * w3; acc.w += v3.w * w3;
        acc.x += v4.x * w4; acc.y += v4.y * w4; acc.z += v4.z * w4; acc.w += v4.w * w4;
        acc.x += v5.x * w5; acc.y += v5.y * w5; acc.z += v5.z * w5; acc.w += v5.w * w5;
        acc.x += v6.x * w6; acc.y += v6.y * w6; acc.z += v6.z * w6; acc.w += v6.w * w6;
        acc.x += v7.x * w7; acc.y += v7.y * w7; acc.z += v7.z * w7; acc.w += v7.w * w7;
    }
    for (; e + 4 <= end; e += 4) {
        int2 r0 = edges[e + 0], r1 = edges[e + 1], r2 = edges[e + 2], r3 = edges[e + 3];
        float4 v0 = h4_to_f4(hw2[(size_t)r0.x * TPD + j]);
        float4 v1 = h4_to_f4(hw2[(size_t)r1.x * TPD + j]);
        float4 v2 = h4_to_f4(hw2[(size_t)r2.x * TPD + j]);
        float4 v3 = h4_to_f4(hw2[(size_t)r3.x * TPD + j]);
        float w0 = __int_as_float(r0.y), w1 = __int_as_float(r1.y);
        float w2 = __int_as_float(r2.y), w3 = __int_as_float(r3.y);
        acc.x += v0.x * w0; acc.y += v0.y * w0; acc.z += v0.z * w0; acc.w += v0.w * w0;
        acc.x += v1.x * w1; acc.y += v1.y * w1; acc.z += v1.z * w1; acc.w += v1.w * w1;
        acc.x += v2.x * w2; acc.y += v2.y * w2; acc.z += v2.z * w2; acc.w += v2.w * w2;
        acc.x += v3.x * w3; acc.y += v3.y * w3; acc.z += v3.z * w3; acc.w += v3.w * w3;
    }
    for (; e < end; ++e) {
        int2 er = edges[e];
        float w = __int_as_float(er.y);
        float4 v = h4_to_f4(hw2[(size_t)er.x * TPD + j]);
        acc.x += v.x * w; acc.y += v.y * w; acc.z += v.z * w; acc.w += v.w * w;
    }

    if (RELU) {
        acc.x = fmaxf(acc.x, 0.f); acc.y = fmaxf(acc.y, 0.f);
        acc.z = fmaxf(acc.z, 0.f); acc.w = fmaxf(acc.w, 0.f);
    }
    if (F16OUT) {
        uint2 q = make_uint2(pack_h2(acc.x, acc.y), pack_h2(acc.z, acc.w));
        ((uint2*)outp)[(size_t)d * TPD + j] = q;
    } else {
        ((float4*)outp)[(size_t)d * TPD + j] = acc;
    }
}

extern "C" void kernel_launch(void* const* d_in, const int* in_sizes, int n_in,
                              void* d_out, int out_size, void* d_ws, size_t ws_size,
                              hipStream_t stream) {
    const float* x  = (const float*)d_in[0];
    const float* W1 = (const float*)d_in[1];
    const float* b1 = (const float*)d_in[2];
    const float* W2 = (const float*)d_in[3];
    const float* b2 = (const float*)d_in[4];
    const float* W3 = (const float*)d_in[5];
    const float* b3 = (const float*)d_in[6];
    const int*   ei = (const int*)d_in[7];

    const int N = in_sizes[0] / 128;
    const int E = in_sizes[7] / 2;
    const int* rowi = ei;       // edge_index[0] = sources
    const int* coli = ei + E;   // edge_index[1] = targets

    float* out = (float*)d_out;

    // workspace carve-up (256B aligned)
    char* ws = (char*)d_ws;
    size_t off = 0;
    auto alloc = [&](size_t bytes) -> void* {
        void* p = ws + off;
        off = (off + bytes + 255) & ~(size_t)255;
        return p;
    };
    const int NB = (N + 255) / 256;
    float* dinv     = (float*)alloc((size_t)N * 4);
    int*   counts   = (int*)  alloc(((size_t)N + 4) * 4);  // int4-padded
    int*   offsets  = (int*)  alloc((size_t)(N + 1) * 4);
    int*   cursor   = (int*)  alloc((size_t)N * 4);
    int*   blocksum = (int*)  alloc((size_t)NB * 4);
    int*   blockoff = (int*)  alloc((size_t)NB * 4);
    int2*  edges    = (int2*) alloc((size_t)E * 8);
    __half* x16     = (__half*)alloc((size_t)N * 128 * 2);
    __half* hw16    = (__half*)alloc((size_t)N * 128 * 2);
    __half* h16     = (__half*)alloc((size_t)N * 128 * 2);

    // ---- degree / norm / CSR  +  x -> f16 ----
    const int n4 = (N + 3) / 4;
    zero_counts_kernel<<<(n4 + 255) / 256, 256, 0, stream>>>((int4*)counts, n4);
    count_edges_kernel<<<(E + 255) / 256, 256, 0, stream>>>(coli, counts, E);
    block_sum_kernel<<<NB, 256, 0, stream>>>(counts, blocksum, N);
    scan_sums_kernel<<<1, 256, 0, stream>>>(blocksum, blockoff, offsets, NB, N);
    write_offsets_kernel<<<NB, 256, 0, stream>>>(counts, blockoff, offsets, cursor, dinv, N);
    fill_csr_kernel<<<(E + 255) / 256, 256, 0, stream>>>(rowi, coli, offsets, cursor, dinv, edges, E);
    const int xc4 = N * 128 / 4;
    f32_to_f16_kernel<<<(xc4 + 255) / 256, 256, 0, stream>>>((const float4*)x, (uint2*)x16, xc4);

    // ---- layer 1 ----
    gemm16_kernel<128><<<(N + 127) / 128, 256, 0, stream>>>(x16, W1, hw16, N);
    agg_kernel<128, true, true><<<(N + 7) / 8, 256, 0, stream>>>(hw16, offsets, edges, dinv, b1, h16, N);

    // ---- layer 2 ----
    gemm16_kernel<128><<<(N + 127) / 128, 256, 0, stream>>>(h16, W2, hw16, N);
    agg_kernel<128, true, true><<<(N + 7) / 8, 256, 0, stream>>>(hw16, offsets, edges, dinv, b2, h16, N);

    // ---- layer 3 (no relu), width 64, f32 out ----
    gemm16_kernel<64><<<(N + 127) / 128, 256, 0, stream>>>(h16, W3, hw16, N);
    agg_kernel<64, false, false><<<(N + 15) / 16, 256, 0, stream>>>(hw16, offsets, edges, dinv, b3, out, N);
}